// Round 4
// baseline (66.536 us; speedup 1.0000x reference)
//
#include <hip/hip_runtime.h>

// TriangleScene: image-method specular path tracing validity check.
// T=2, R=4, P=1000, ORDER=2, NF=600, NV=3000 (hard structural assumptions:
// ORDER==2, NF<=MAXF; NV<=MAXV has a global-memory fallback). All float math
// uses __f*_rn intrinsics in the reference's evaluation order so FMA
// contraction can't flip borderline comparisons.
//
// R4 structure: ONE kernel, one block = 64 paths (125 blocks).
//   phase 0a: ALL vertices -> LDS via coalesced float4 loads (36 KB).
//             (R3 post-mortem: the table build's dependent scattered gather
//             was ~2-4 us of exposed latency at 1 wave/SIMD; staging verts
//             coalesced first removes the global gather chain.)
//   phase 0b: build NF-triangle {v0,e1,e2} table in LDS, gathering from LDS.
//   phase 1 : one LANE per path (wave 0) — image-method chain + pre-gate,
//             normals on the fly, outputs written, survivors compacted to
//             LDS via LDS atomicAdd.
//   phase 2 : 4 waves sweep occlusion for the block's survivors
//             (ballot early-exit per 64-tri chunk), clearing mask if blocked.

#define DEV __device__ __forceinline__
#define MAXF 1024      // LDS triangle-table capacity (NF=600 here)
#define MAXV 3072      // LDS vertex-table capacity (NV=3000 here)
#define PPB  64        // paths per block

struct F3 { float x, y, z; };

DEV float fmul(float a, float b) { return __fmul_rn(a, b); }
DEV float fadd(float a, float b) { return __fadd_rn(a, b); }
DEV float fsub(float a, float b) { return __fsub_rn(a, b); }

DEV F3 f3sub(F3 a, F3 b) { return { fsub(a.x,b.x), fsub(a.y,b.y), fsub(a.z,b.z) }; }
// sum order matches np.sum over last axis: (x + y) + z
DEV float f3dot(F3 a, F3 b) {
  return fadd(fadd(fmul(a.x,b.x), fmul(a.y,b.y)), fmul(a.z,b.z));
}
DEV F3 f3cross(F3 a, F3 b) {
  return { fsub(fmul(a.y,b.z), fmul(a.z,b.y)),
           fsub(fmul(a.z,b.x), fmul(a.x,b.z)),
           fsub(fmul(a.x,b.y), fmul(a.y,b.x)) };
}

struct MTRes { float t; bool hit; };

// Moller-Trumbore, exactly mirroring _rays_intersect_triangles
DEV MTRes mt(F3 ro, F3 rd, F3 v0, F3 e1, F3 e2) {
  F3 h = f3cross(rd, e2);
  float a = f3dot(e1, h);
  bool conda = fabsf(a) < 1e-6f;
  float f = conda ? 0.0f : __fdiv_rn(1.0f, a);
  F3 s = f3sub(ro, v0);
  float u = fmul(f, f3dot(s, h));
  F3 q = f3cross(s, e1);
  float v = fmul(f, f3dot(rd, q));
  float tt = fmul(f, f3dot(e2, q));
  bool hit = (!conda) && (u >= 0.0f) && (u <= 1.0f) && (v >= 0.0f)
             && (fadd(u, v) <= 1.0f) && (tt > 1e-6f);
  return { tt, hit };
}

__global__ __launch_bounds__(256) void k_fused(
    const float* __restrict__ verts, const int* __restrict__ tris,
    const float* __restrict__ txv, const float* __restrict__ rxv,
    const int* __restrict__ pc, float* __restrict__ out,
    int T, int R, int P, int nf, int nv)
{
  __shared__ __align__(16) float s_v[MAXV * 3];   // 36 KB vertex stage
  // 9 floats per tri: v0.xyz, e1.xyz, e2.xyz. Stride 9 words -> <=2-way bank
  // aliasing on lane-strided reads (free on CDNA4).
  __shared__ float s_tri[MAXF * 9];
  __shared__ float s_ray[PPB * 18];   // survivor rays: ro0,ro1,ro2,rd0,rd1,rd2
  __shared__ int   s_pw[PPB];         // survivor path ids
  __shared__ int   s_cnt;

  const int tid = threadIdx.x;
  if (tid == 0) s_cnt = 0;

  // ---- phase 0a: coalesced vertex stage into LDS ----
  const int nv3 = nv * 3;
  const bool vlds = (nv3 <= MAXV * 3);
  if (vlds) {
    const float4* v4 = reinterpret_cast<const float4*>(verts);
    float4* s4 = reinterpret_cast<float4*>(s_v);
    const int n4 = nv3 >> 2;
    for (int i = tid; i < n4; i += 256) s4[i] = v4[i];          // independent
    for (int i = (n4 << 2) + tid; i < nv3; i += 256) s_v[i] = verts[i];
  }
  __syncthreads();
  const float* vsrc = vlds ? s_v : verts;

  // ---- phase 0b: build triangle table in LDS (gather from LDS verts) ----
  for (int f = tid; f < nf; f += 256) {
    int i0 = tris[3*f+0], i1 = tris[3*f+1], i2 = tris[3*f+2];
    F3 v0 = { vsrc[3*i0], vsrc[3*i0+1], vsrc[3*i0+2] };
    F3 v1 = { vsrc[3*i1], vsrc[3*i1+1], vsrc[3*i1+2] };
    F3 v2 = { vsrc[3*i2], vsrc[3*i2+1], vsrc[3*i2+2] };
    F3 e1 = f3sub(v1, v0);
    F3 e2 = f3sub(v2, v0);
    float* d = s_tri + f * 9;
    d[0] = v0.x; d[1] = v0.y; d[2] = v0.z;
    d[3] = e1.x; d[4] = e1.y; d[5] = e1.z;
    d[6] = e2.x; d[7] = e2.y; d[8] = e2.z;
  }
  __syncthreads();

  const int nPaths = T * R * P;
  const int pw = blockIdx.x * PPB + tid;

  // ---- phase 1: one lane per path (wave 0 only; waves 1-3 wait) ----
  if (tid < PPB && pw < nPaths) {
    const int p  = pw % P;
    const int tr = pw / P;
    const int r  = tr % R;
    const int t  = tr / R;

    const int f0 = pc[2*p + 0];
    const int f1 = pc[2*p + 1];
    const float* t0 = s_tri + f0 * 9;
    const float* t1 = s_tri + f1 * 9;
    F3 v00 = {t0[0],t0[1],t0[2]}, e10 = {t0[3],t0[4],t0[5]}, e20 = {t0[6],t0[7],t0[8]};
    F3 v01 = {t1[0],t1[1],t1[2]}, e11 = {t1[3],t1[4],t1[5]}, e21 = {t1[6],t1[7],t1[8]};

    // normals, same op order as reference: fn = cross(e1,e2); n = fn/||fn||
    F3 fn0 = f3cross(e10, e20);
    float nrm0 = __fsqrt_rn(f3dot(fn0, fn0));
    F3 n0 = { __fdiv_rn(fn0.x, nrm0), __fdiv_rn(fn0.y, nrm0), __fdiv_rn(fn0.z, nrm0) };
    F3 fn1 = f3cross(e11, e21);
    float nrm1 = __fsqrt_rn(f3dot(fn1, fn1));
    F3 n1 = { __fdiv_rn(fn1.x, nrm1), __fdiv_rn(fn1.y, nrm1), __fdiv_rn(fn1.z, nrm1) };

    F3 TX = { txv[3*t], txv[3*t+1], txv[3*t+2] };
    F3 RX = { rxv[3*r], rxv[3*r+1], rxv[3*r+2] };

    // forward scan: images. img = carry - (2*dot(carry-mv, mn)) * mn
    float d0  = f3dot(f3sub(TX, v00), n0);
    float td0 = fmul(2.0f, d0);
    F3 img1 = { fsub(TX.x, fmul(td0, n0.x)), fsub(TX.y, fmul(td0, n0.y)), fsub(TX.z, fmul(td0, n0.z)) };
    float d1  = f3dot(f3sub(img1, v01), n1);
    float td1 = fmul(2.0f, d1);
    F3 img2 = { fsub(img1.x, fmul(td1, n1.x)), fsub(img1.y, fmul(td1, n1.y)), fsub(img1.z, fmul(td1, n1.z)) };

    // backward scan (reverse): mirror1 first, then mirror0
    F3 u2 = f3sub(RX, img2);
    float un = f3dot(u2, n1);
    float vn = f3dot(f3sub(img2, v01), n1);
    float tb = (un == 0.0f) ? 0.0f : __fdiv_rn(-vn, un);
    F3 p1 = { fadd(img2.x, fmul(tb, u2.x)), fadd(img2.y, fmul(tb, u2.y)), fadd(img2.z, fmul(tb, u2.z)) };

    F3 u1 = f3sub(p1, img1);
    un = f3dot(u1, n0);
    vn = f3dot(f3sub(img1, v00), n0);
    tb = (un == 0.0f) ? 0.0f : __fdiv_rn(-vn, un);
    F3 p0 = { fadd(img1.x, fmul(tb, u1.x)), fadd(img1.y, fmul(tb, u1.y)), fadd(img1.z, fmul(tb, u1.z)) };

    // full_paths = [TX, p0, p1, RX]; rays = consecutive diffs
    F3 ro0 = TX, ro1 = p0, ro2 = p1;
    F3 rd0 = f3sub(p0, TX), rd1 = f3sub(p1, p0), rd2 = f3sub(RX, p1);

    // hit_in: ray i vs mirror triangle i
    MTRes h0 = mt(ro0, rd0, v00, e10, e20);
    MTRes h1 = mt(ro1, rd1, v01, e11, e21);
    bool inside = h0.hit && h1.hit;

    // valid_refl: d_prev[i]*d_next[i] >= 0 for both mirrors
    float dp0 = f3dot(f3sub(TX, v00), n0);
    float dn0 = f3dot(f3sub(p1, v00), n0);
    float dp1 = f3dot(f3sub(p0, v01), n1);
    float dn1 = f3dot(f3sub(RX, v01), n1);
    bool vrefl = (fmul(dp0, dn0) >= 0.0f) && (fmul(dp1, dn1) >= 0.0f);

    // too_small: any segment shorter than MIN_LEN
    bool toosmall = (f3dot(rd0, rd0) < 1.2e-6f) ||
                    (f3dot(rd1, rd1) < 1.2e-6f) ||
                    (f3dot(rd2, rd2) < 1.2e-6f);

    bool pre = inside && vrefl && !toosmall;

    // outputs (mask tentatively = pre; phase 2 clears blocked survivors)
    float4* fp = reinterpret_cast<float4*>(out) + (size_t)pw * 3;
    fp[0] = make_float4(TX.x, TX.y, TX.z, p0.x);
    fp[1] = make_float4(p0.y, p0.z, p1.x, p1.y);
    fp[2] = make_float4(p1.z, RX.x, RX.y, RX.z);
    float4* ob = reinterpret_cast<float4*>(out + (size_t)nPaths * 12) + pw;
    *ob = make_float4((float)t, (float)f0, (float)f1, (float)r);
    out[(size_t)nPaths * 16 + pw] = pre ? 1.0f : 0.0f;

    if (pre) {
      int idx = atomicAdd(&s_cnt, 1);     // LDS atomic, block-local
      float* rr = s_ray + idx * 18;
      rr[0]=ro0.x;  rr[1]=ro0.y;  rr[2]=ro0.z;
      rr[3]=ro1.x;  rr[4]=ro1.y;  rr[5]=ro1.z;
      rr[6]=ro2.x;  rr[7]=ro2.y;  rr[8]=ro2.z;
      rr[9]=rd0.x;  rr[10]=rd0.y; rr[11]=rd0.z;
      rr[12]=rd1.x; rr[13]=rd1.y; rr[14]=rd1.z;
      rr[15]=rd2.x; rr[16]=rd2.y; rr[17]=rd2.z;
      s_pw[idx] = pw;
    }
  }
  __syncthreads();

  // ---- phase 2: waves sweep occlusion for this block's survivors ----
  const int S = s_cnt;
  const int lane = tid & 63;
  const int wid  = tid >> 6;
  for (int s = wid; s < S; s += 4) {
    const float* rr = s_ray + s * 18;    // wave-uniform addr -> LDS broadcast
    F3 ro0 = {rr[0],rr[1],rr[2]},   ro1 = {rr[3],rr[4],rr[5]},   ro2 = {rr[6],rr[7],rr[8]};
    F3 rd0 = {rr[9],rr[10],rr[11]}, rd1 = {rr[12],rr[13],rr[14]}, rd2 = {rr[15],rr[16],rr[17]};

    bool blocked = false;
    for (int base = 0; base < nf; base += 64) {
      const int f = base + lane;
      bool blk = false;
      if (f < nf) {
        const float* tt = s_tri + f * 9;
        F3 w0  = {tt[0], tt[1], tt[2]};
        F3 we1 = {tt[3], tt[4], tt[5]};
        F3 we2 = {tt[6], tt[7], tt[8]};
        MTRes hb0 = mt(ro0, rd0, w0, we1, we2);
        MTRes hb1 = mt(ro1, rd1, w0, we1, we2);
        MTRes hb2 = mt(ro2, rd2, w0, we1, we2);
        blk = (hb0.hit && (hb0.t < 0.999f))
           || (hb1.hit && (hb1.t < 0.999f))
           || (hb2.hit && (hb2.t < 0.999f));
      }
      if (__ballot(blk) != 0ULL) { blocked = true; break; }
    }
    if (blocked && lane == 0) out[(size_t)(T*R*P) * 16 + s_pw[s]] = 0.0f;
  }
}

extern "C" void kernel_launch(void* const* d_in, const int* in_sizes, int n_in,
                              void* d_out, int out_size, void* d_ws, size_t ws_size,
                              hipStream_t stream) {
  const float* mesh_v = (const float*)d_in[0];   // (NV,3) f32
  const int*   mesh_t = (const int*)d_in[1];     // (NF,3) i32
  const float* txv    = (const float*)d_in[2];   // (T,3)  f32
  const float* rxv    = (const float*)d_in[3];   // (R,3)  f32
  const int*   pc     = (const int*)d_in[4];     // (P,2)  i32

  const int NV = in_sizes[0] / 3;
  const int NF = in_sizes[1] / 3;                // must be <= MAXF (600 here)
  const int T  = in_sizes[2] / 3;
  const int R  = in_sizes[3] / 3;
  const int P  = in_sizes[4] / 2;                // ORDER == 2
  const int nPaths = T * R * P;

  const int blocks = (nPaths + PPB - 1) / PPB;   // 125 blocks @ 8000 paths
  k_fused<<<blocks, 256, 0, stream>>>(mesh_v, mesh_t, txv, rxv, pc,
                                      (float*)d_out, T, R, P, NF, NV);
}

// Round 6
// 64.115 us; speedup vs baseline: 1.0378x; 1.0378x over previous
//
#include <hip/hip_runtime.h>

// TriangleScene: image-method specular path tracing validity check.
// T=2, R=4, P=1000, ORDER=2, NF=600 (hard structural assumptions: ORDER==2,
// NF <= MAXF). All float math uses __f*_rn intrinsics in the reference's
// evaluation order so FMA contraction can't flip borderline comparisons.
//
// R6 = resubmit of R5 (= R3, best measured: 64.3 us); R5's bench failed on
// container acquisition, not on the kernel. Structure:
//   ONE kernel. Each block (256 thr, 4 waves) owns PPB=64 paths:
//   phase 0: cooperatively build the full NF-triangle {v0,e1,e2} table in LDS.
//   phase 1: one LANE per path — image-method chain + pre-gate, mirror
//            normals on the fly, outputs written, survivors compacted into
//            LDS via LDS atomicAdd.
//   phase 2: the block's 4 waves sweep occlusion for the block's survivors
//            (ballot early-exit per 64-tri chunk), clearing mask if blocked.
// R4 lesson kept: do NOT stage vertices in LDS — mesh data is L1/L2-resident
// and staging regressed +2.2 us.

#define DEV __device__ __forceinline__
#define MAXF 1024      // LDS triangle-table capacity (NF=600 in this problem)
#define PPB  64        // paths per block

struct F3 { float x, y, z; };

DEV float fmul(float a, float b) { return __fmul_rn(a, b); }
DEV float fadd(float a, float b) { return __fadd_rn(a, b); }
DEV float fsub(float a, float b) { return __fsub_rn(a, b); }

DEV F3 f3sub(F3 a, F3 b) { return { fsub(a.x,b.x), fsub(a.y,b.y), fsub(a.z,b.z) }; }
// sum order matches np.sum over last axis: (x + y) + z
DEV float f3dot(F3 a, F3 b) {
  return fadd(fadd(fmul(a.x,b.x), fmul(a.y,b.y)), fmul(a.z,b.z));
}
DEV F3 f3cross(F3 a, F3 b) {
  return { fsub(fmul(a.y,b.z), fmul(a.z,b.y)),
           fsub(fmul(a.z,b.x), fmul(a.x,b.z)),
           fsub(fmul(a.x,b.y), fmul(a.y,b.x)) };
}

struct MTRes { float t; bool hit; };

// Moller-Trumbore, exactly mirroring _rays_intersect_triangles
DEV MTRes mt(F3 ro, F3 rd, F3 v0, F3 e1, F3 e2) {
  F3 h = f3cross(rd, e2);
  float a = f3dot(e1, h);
  bool conda = fabsf(a) < 1e-6f;
  float f = conda ? 0.0f : __fdiv_rn(1.0f, a);
  F3 s = f3sub(ro, v0);
  float u = fmul(f, f3dot(s, h));
  F3 q = f3cross(s, e1);
  float v = fmul(f, f3dot(rd, q));
  float tt = fmul(f, f3dot(e2, q));
  bool hit = (!conda) && (u >= 0.0f) && (u <= 1.0f) && (v >= 0.0f)
             && (fadd(u, v) <= 1.0f) && (tt > 1e-6f);
  return { tt, hit };
}

__global__ __launch_bounds__(256) void k_fused(
    const float* __restrict__ verts, const int* __restrict__ tris,
    const float* __restrict__ txv, const float* __restrict__ rxv,
    const int* __restrict__ pc, float* __restrict__ out,
    int T, int R, int P, int nf)
{
  // 9 floats per tri: v0.xyz, e1.xyz, e2.xyz. Stride 9 words -> <=2-way bank
  // aliasing on lane-strided reads (free on CDNA4).
  __shared__ float s_tri[MAXF * 9];
  __shared__ float s_ray[PPB * 18];   // survivor rays: ro0,ro1,ro2,rd0,rd1,rd2
  __shared__ int   s_pw[PPB];         // survivor path ids
  __shared__ int   s_cnt;

  const int tid = threadIdx.x;
  if (tid == 0) s_cnt = 0;

  // ---- phase 0: build triangle table in LDS ----
  for (int f = tid; f < nf; f += 256) {
    int i0 = tris[3*f+0], i1 = tris[3*f+1], i2 = tris[3*f+2];
    F3 v0 = { verts[3*i0], verts[3*i0+1], verts[3*i0+2] };
    F3 v1 = { verts[3*i1], verts[3*i1+1], verts[3*i1+2] };
    F3 v2 = { verts[3*i2], verts[3*i2+1], verts[3*i2+2] };
    F3 e1 = f3sub(v1, v0);
    F3 e2 = f3sub(v2, v0);
    float* d = s_tri + f * 9;
    d[0] = v0.x; d[1] = v0.y; d[2] = v0.z;
    d[3] = e1.x; d[4] = e1.y; d[5] = e1.z;
    d[6] = e2.x; d[7] = e2.y; d[8] = e2.z;
  }
  __syncthreads();

  const int nPaths = T * R * P;
  const int pw = blockIdx.x * PPB + tid;

  // ---- phase 1: one lane per path (wave 0 only; waves 1-3 wait) ----
  if (tid < PPB && pw < nPaths) {
    const int p  = pw % P;
    const int tr = pw / P;
    const int r  = tr % R;
    const int t  = tr / R;

    const int f0 = pc[2*p + 0];
    const int f1 = pc[2*p + 1];
    const float* t0 = s_tri + f0 * 9;
    const float* t1 = s_tri + f1 * 9;
    F3 v00 = {t0[0],t0[1],t0[2]}, e10 = {t0[3],t0[4],t0[5]}, e20 = {t0[6],t0[7],t0[8]};
    F3 v01 = {t1[0],t1[1],t1[2]}, e11 = {t1[3],t1[4],t1[5]}, e21 = {t1[6],t1[7],t1[8]};

    // normals, same op order as reference: fn = cross(e1,e2); n = fn/||fn||
    F3 fn0 = f3cross(e10, e20);
    float nrm0 = __fsqrt_rn(f3dot(fn0, fn0));
    F3 n0 = { __fdiv_rn(fn0.x, nrm0), __fdiv_rn(fn0.y, nrm0), __fdiv_rn(fn0.z, nrm0) };
    F3 fn1 = f3cross(e11, e21);
    float nrm1 = __fsqrt_rn(f3dot(fn1, fn1));
    F3 n1 = { __fdiv_rn(fn1.x, nrm1), __fdiv_rn(fn1.y, nrm1), __fdiv_rn(fn1.z, nrm1) };

    F3 TX = { txv[3*t], txv[3*t+1], txv[3*t+2] };
    F3 RX = { rxv[3*r], rxv[3*r+1], rxv[3*r+2] };

    // forward scan: images. img = carry - (2*dot(carry-mv, mn)) * mn
    float d0  = f3dot(f3sub(TX, v00), n0);
    float td0 = fmul(2.0f, d0);
    F3 img1 = { fsub(TX.x, fmul(td0, n0.x)), fsub(TX.y, fmul(td0, n0.y)), fsub(TX.z, fmul(td0, n0.z)) };
    float d1  = f3dot(f3sub(img1, v01), n1);
    float td1 = fmul(2.0f, d1);
    F3 img2 = { fsub(img1.x, fmul(td1, n1.x)), fsub(img1.y, fmul(td1, n1.y)), fsub(img1.z, fmul(td1, n1.z)) };

    // backward scan (reverse): mirror1 first, then mirror0
    F3 u2 = f3sub(RX, img2);
    float un = f3dot(u2, n1);
    float vn = f3dot(f3sub(img2, v01), n1);
    float tb = (un == 0.0f) ? 0.0f : __fdiv_rn(-vn, un);
    F3 p1 = { fadd(img2.x, fmul(tb, u2.x)), fadd(img2.y, fmul(tb, u2.y)), fadd(img2.z, fmul(tb, u2.z)) };

    F3 u1 = f3sub(p1, img1);
    un = f3dot(u1, n0);
    vn = f3dot(f3sub(img1, v00), n0);
    tb = (un == 0.0f) ? 0.0f : __fdiv_rn(-vn, un);
    F3 p0 = { fadd(img1.x, fmul(tb, u1.x)), fadd(img1.y, fmul(tb, u1.y)), fadd(img1.z, fmul(tb, u1.z)) };

    // full_paths = [TX, p0, p1, RX]; rays = consecutive diffs
    F3 ro0 = TX, ro1 = p0, ro2 = p1;
    F3 rd0 = f3sub(p0, TX), rd1 = f3sub(p1, p0), rd2 = f3sub(RX, p1);

    // hit_in: ray i vs mirror triangle i
    MTRes h0 = mt(ro0, rd0, v00, e10, e20);
    MTRes h1 = mt(ro1, rd1, v01, e11, e21);
    bool inside = h0.hit && h1.hit;

    // valid_refl: d_prev[i]*d_next[i] >= 0 for both mirrors
    float dp0 = f3dot(f3sub(TX, v00), n0);
    float dn0 = f3dot(f3sub(p1, v00), n0);
    float dp1 = f3dot(f3sub(p0, v01), n1);
    float dn1 = f3dot(f3sub(RX, v01), n1);
    bool vrefl = (fmul(dp0, dn0) >= 0.0f) && (fmul(dp1, dn1) >= 0.0f);

    // too_small: any segment shorter than MIN_LEN
    bool toosmall = (f3dot(rd0, rd0) < 1.2e-6f) ||
                    (f3dot(rd1, rd1) < 1.2e-6f) ||
                    (f3dot(rd2, rd2) < 1.2e-6f);

    bool pre = inside && vrefl && !toosmall;

    // outputs (mask tentatively = pre; phase 2 clears blocked survivors)
    float4* fp = reinterpret_cast<float4*>(out) + (size_t)pw * 3;
    fp[0] = make_float4(TX.x, TX.y, TX.z, p0.x);
    fp[1] = make_float4(p0.y, p0.z, p1.x, p1.y);
    fp[2] = make_float4(p1.z, RX.x, RX.y, RX.z);
    float4* ob = reinterpret_cast<float4*>(out + (size_t)nPaths * 12) + pw;
    *ob = make_float4((float)t, (float)f0, (float)f1, (float)r);
    out[(size_t)nPaths * 16 + pw] = pre ? 1.0f : 0.0f;

    if (pre) {
      int idx = atomicAdd(&s_cnt, 1);     // LDS atomic, block-local
      float* rr = s_ray + idx * 18;
      rr[0]=ro0.x;  rr[1]=ro0.y;  rr[2]=ro0.z;
      rr[3]=ro1.x;  rr[4]=ro1.y;  rr[5]=ro1.z;
      rr[6]=ro2.x;  rr[7]=ro2.y;  rr[8]=ro2.z;
      rr[9]=rd0.x;  rr[10]=rd0.y; rr[11]=rd0.z;
      rr[12]=rd1.x; rr[13]=rd1.y; rr[14]=rd1.z;
      rr[15]=rd2.x; rr[16]=rd2.y; rr[17]=rd2.z;
      s_pw[idx] = pw;
    }
  }
  __syncthreads();

  // ---- phase 2: waves sweep occlusion for this block's survivors ----
  const int S = s_cnt;
  const int lane = tid & 63;
  const int wid  = tid >> 6;
  for (int s = wid; s < S; s += 4) {
    const float* rr = s_ray + s * 18;    // wave-uniform addr -> LDS broadcast
    F3 ro0 = {rr[0],rr[1],rr[2]},   ro1 = {rr[3],rr[4],rr[5]},   ro2 = {rr[6],rr[7],rr[8]};
    F3 rd0 = {rr[9],rr[10],rr[11]}, rd1 = {rr[12],rr[13],rr[14]}, rd2 = {rr[15],rr[16],rr[17]};

    bool blocked = false;
    for (int base = 0; base < nf; base += 64) {
      const int f = base + lane;
      bool blk = false;
      if (f < nf) {
        const float* tt = s_tri + f * 9;
        F3 w0  = {tt[0], tt[1], tt[2]};
        F3 we1 = {tt[3], tt[4], tt[5]};
        F3 we2 = {tt[6], tt[7], tt[8]};
        MTRes hb0 = mt(ro0, rd0, w0, we1, we2);
        MTRes hb1 = mt(ro1, rd1, w0, we1, we2);
        MTRes hb2 = mt(ro2, rd2, w0, we1, we2);
        blk = (hb0.hit && (hb0.t < 0.999f))
           || (hb1.hit && (hb1.t < 0.999f))
           || (hb2.hit && (hb2.t < 0.999f));
      }
      if (__ballot(blk) != 0ULL) { blocked = true; break; }
    }
    if (blocked && lane == 0) out[(size_t)(T*R*P) * 16 + s_pw[s]] = 0.0f;
  }
}

extern "C" void kernel_launch(void* const* d_in, const int* in_sizes, int n_in,
                              void* d_out, int out_size, void* d_ws, size_t ws_size,
                              hipStream_t stream) {
  const float* mesh_v = (const float*)d_in[0];   // (NV,3) f32
  const int*   mesh_t = (const int*)d_in[1];     // (NF,3) i32
  const float* txv    = (const float*)d_in[2];   // (T,3)  f32
  const float* rxv    = (const float*)d_in[3];   // (R,3)  f32
  const int*   pc     = (const int*)d_in[4];     // (P,2)  i32

  const int NF = in_sizes[1] / 3;                // must be <= MAXF (600 here)
  const int T  = in_sizes[2] / 3;
  const int R  = in_sizes[3] / 3;
  const int P  = in_sizes[4] / 2;                // ORDER == 2
  const int nPaths = T * R * P;

  const int blocks = (nPaths + PPB - 1) / PPB;   // 125 blocks @ 8000 paths
  k_fused<<<blocks, 256, 0, stream>>>(mesh_v, mesh_t, txv, rxv, pc,
                                      (float*)d_out, T, R, P, NF);
}